// Round 7
// baseline (280.050 us; speedup 1.0000x reference)
//
#include <hip/hip_runtime.h>
#include <hip/hip_bf16.h>
#include <math.h>

#define B_ 32
#define S_ 1024
#define E_ 512
#define T_ 128
#define Q_ 256
#define H_ 4
#define F_ (H_ * Q_)      // 1024
#define M_ (B_ * S_)      // 32768

typedef __bf16 bf16x8 __attribute__((ext_vector_type(8)));
typedef float f32x4 __attribute__((ext_vector_type(4)));
typedef unsigned int uint32;

__device__ __forceinline__ float lrelu(float x) { return x > 0.0f ? x : 0.01f * x; }
__device__ __forceinline__ uint32 pack_hi2(float a, float b) {
    return (__float_as_uint(a) >> 16) | (__float_as_uint(b) & 0xffff0000u);
}
__device__ __forceinline__ float resid(float f) {
    return f - __uint_as_float(__float_as_uint(f) & 0xffff0000u);
}

#define GLOAD_LDS16(g, l)                                                       \
    __builtin_amdgcn_global_load_lds(                                           \
        (const __attribute__((address_space(1))) void*)(g),                     \
        (__attribute__((address_space(3))) void*)(l), 16, 0, 0)

#define SRC_BLOCKS 16384      // src windows / 16
#define W_BLOCKS   512        // W_src windows / 16
#define HS_BLOCKS  1024       // head-select: wave per (t,b), 4 waves/block

// ---------------------------------------------------------------------------
// Prep: repack src -> apk and W_src -> wpk (hi/lo bf16 per 64-float window;
// out-of-place into ws when it fits, else in-place; in-place-safe pattern) +
// per-(t,b) argmax head into best[].
// ---------------------------------------------------------------------------
__global__ __launch_bounds__(256) void prep_kernel(
    const float* src, float* apk, const float* wsrc, float* wpk,
    const float* __restrict__ qv, const float* __restrict__ Wopt,
    int* __restrict__ best) {
    const int blk = blockIdx.x;
    if (blk < SRC_BLOCKS + W_BLOCKS) {
        const float* inb = (blk < SRC_BLOCKS) ? src : wsrc;
        float* outb = (blk < SRC_BLOCKS) ? apk : wpk;
        const size_t woff = (size_t)((blk < SRC_BLOCKS) ? blk : (blk - SRC_BLOCKS)) * 16;
        const int tid = threadIdx.x;
        const size_t c = woff + (tid >> 4);
        const int j = tid & 15;
        const float* rp = inb + c * 64;
        char* wp = (char*)(outb + c * 64);
        float4 v = *(const float4*)(rp + j * 4);
        uint32 h0 = pack_hi2(v.x, v.y), h1 = pack_hi2(v.z, v.w);
        uint32 l0 = pack_hi2(resid(v.x), resid(v.y));
        uint32 l1 = pack_hi2(resid(v.z), resid(v.w));
        *(uint2*)(wp + j * 8)       = make_uint2(h0, h1);
        *(uint2*)(wp + 128 + j * 8) = make_uint2(l0, l1);
    } else {
        const int wave = threadIdx.x >> 6, lane = threadIdx.x & 63;
        const int idx = (blk - SRC_BLOCKS - W_BLOCKS) * 4 + wave;   // t*B + b
        const float4 qq = *(const float4*)(qv + (size_t)idx * Q_ + lane * 4);
        float s[4];
#pragma unroll
        for (int h = 0; h < 4; ++h) {
            float4 w = *(const float4*)(Wopt + h * Q_ + lane * 4);
            s[h] = qq.x * w.x + qq.y * w.y + qq.z * w.z + qq.w * w.w;
        }
#pragma unroll
        for (int off = 32; off >= 1; off >>= 1) {
#pragma unroll
            for (int h = 0; h < 4; ++h) s[h] += __shfl_down(s[h], off);
        }
        if (lane == 0) {
            int bh = 0; float bs = s[0];
            if (s[1] > bs) { bs = s[1]; bh = 1; }
            if (s[2] > bs) { bs = s[2]; bh = 2; }
            if (s[3] > bs) { bs = s[3]; bh = 3; }
            best[idx] = bh;
        }
    }
}

// ---------------------------------------------------------------------------
// Fused proj+score, 256x256 tiles (8 waves, wave-tile 128x64, BK=32).
// Theory (r6 counters): K-loop is LDS-throughput-bound (LDS cyc : MFMA cyc
// = 1020:233 per 128^2 block-step, matching MfmaUtil 37%). 256^2 improves
// LDS-bytes/FLOP 1.5x and amortizes per-step barrier stalls 4x. Sync
// skeleton = r6's verified counted-vmcnt dbuf (8 gload_lds per batch,
// vmcnt(8), same ledger). Row format & 2-bit XOR swizzle unchanged (64B
// rows, slot = g ^ ((row>>1)&3); all row bases = 0 mod 16 so per-lane XOR
// terms identical to r6). Each block owns a FULL head (bj = h): complete
// logits, single output buf. Epilogue: 4 x 64-row P-slices in the freed
// 128 KB LDS; 5-bit granule swizzle gs=(g&24)|((g^row)&7) (2-way reads).
// ---------------------------------------------------------------------------
__global__ __launch_bounds__(512, 2) void proj_score_kernel(
    const unsigned char* __restrict__ Apk,   // repacked src
    const unsigned char* __restrict__ Wpk,   // repacked W_src
    const float* __restrict__ qv,            // (T,B,Q) fp32
    const int* __restrict__ best,            // (T*B)
    float* __restrict__ bufs)                // (T,B,S) logits in ws
{
    __shared__ uint4 smem4[8192];            // 128 KB
    char* smem = (char*)smem4;
    // K-loop dbuf: buf@0, buf@65536; each 64KB: Ah[0,16K) Al[16K,32K)
    //   Bh[32K,48K) Bl[48K,64K)   (256 rows x 64B per section)
    // Epilogue: Ph[0,32K) Pl[32K,64K) (64 rows x 512B)
    //           Qh[64K,80K) Ql[80K,96K) (32 rows x 512B)
    //           tl @98304 (+512), lcnt @98816

    const int bid = blockIdx.x;
    const int xcd = bid & 7;
    const int q_ = bid >> 3;                 // 0..63 within XCD
    const int bi = xcd * 16 + (q_ >> 2);     // 0..127 (M tile, 256 rows)
    const int bj = q_ & 3;                   // head 0..3 (N tile, 256 cols)

    const int tid = threadIdx.x;
    const int wave = tid >> 6, lane = tid & 63;
    const int wm = wave >> 2, wn = wave & 3;  // wave grid 2 x 4
    const int quad = lane >> 4;
    const int fr = lane & 15;
    const int xr = fr & 7;

    const size_t Abase = (size_t)(bi * 256) * 2048;
    const size_t Wbase = (size_t)(bj * 256) * 2048;

    // --- staging lane mapping (16 rows x 4 slots per wave-instr) ---
    const int r16 = lane >> 2;
    const int slot = lane & 3;
    const int sgb = ((slot ^ ((r16 >> 1) & 3)) & 3) * 16;  // pre-swizzled src group
    const unsigned char* gA = Apk + Abase + (size_t)(wave * 32 + r16) * 2048 + sgb;
    const unsigned char* gW = Wpk + Wbase + (size_t)(wave * 32 + r16) * 2048 + sgb;

    // --- compute lane mapping ---
    const int koB = ((quad ^ ((fr >> 1) & 3)) & 3) * 16;   // swizzled read slot

    f32x4 acc[8][4] = {};

#define STAGE(bufb_, ks_) do {                                                 \
    const int hb_ = ((ks_) >> 1) * 256 + ((ks_) & 1) * 64;                     \
    _Pragma("unroll")                                                          \
    for (int c_ = 0; c_ < 2; ++c_) {                                           \
        const unsigned char* a_ = gA + (size_t)c_ * 32768 + hb_;               \
        const unsigned char* w_ = gW + (size_t)c_ * 32768 + hb_;               \
        char* l_ = smem + (bufb_) + wave * 2048 + c_ * 1024;                   \
        GLOAD_LDS16(a_,       l_);                                             \
        GLOAD_LDS16(a_ + 128, l_ + 16384);                                     \
        GLOAD_LDS16(w_,       l_ + 32768);                                     \
        GLOAD_LDS16(w_ + 128, l_ + 49152);                                     \
    }                                                                          \
} while (0)

    STAGE(0, 0);
    STAGE(65536, 1);
    asm volatile("s_waitcnt vmcnt(8)" ::: "memory");   // batch 0 landed
    __builtin_amdgcn_s_barrier();

    int cur = 0;
#pragma unroll 1
    for (int ks = 0; ks < 16; ++ks) {
        bf16x8 ah[8], al[8], bh4[4], bl4[4];
#pragma unroll
        for (int i_ = 0; i_ < 8; ++i_) {
            int ra = (wm * 128 + i_ * 16 + fr) * 64 + koB;
            ah[i_] = *(const bf16x8*)(smem + cur +         ra);
            al[i_] = *(const bf16x8*)(smem + cur + 16384 + ra);
        }
#pragma unroll
        for (int j_ = 0; j_ < 4; ++j_) {
            int rb = (wn * 64 + j_ * 16 + fr) * 64 + koB;
            bh4[j_] = *(const bf16x8*)(smem + cur + 32768 + rb);
            bl4[j_] = *(const bf16x8*)(smem + cur + 49152 + rb);
        }
        asm volatile("s_waitcnt lgkmcnt(0)" ::: "memory");  // my reads of cur done
        __builtin_amdgcn_s_barrier();                       // everyone's reads done
        if (ks < 14) STAGE(cur, ks + 2);                    // overwrite cur (prefetch)
        __builtin_amdgcn_s_setprio(1);
#pragma unroll
        for (int i_ = 0; i_ < 8; ++i_)
#pragma unroll
            for (int j_ = 0; j_ < 4; ++j_) {
                acc[i_][j_] = __builtin_amdgcn_mfma_f32_16x16x32_bf16(ah[i_], bh4[j_], acc[i_][j_], 0, 0, 0);
                acc[i_][j_] = __builtin_amdgcn_mfma_f32_16x16x32_bf16(ah[i_], bl4[j_], acc[i_][j_], 0, 0, 0);
                acc[i_][j_] = __builtin_amdgcn_mfma_f32_16x16x32_bf16(al[i_], bh4[j_], acc[i_][j_], 0, 0, 0);
            }
        __builtin_amdgcn_s_setprio(0);
        if (ks < 14) {
            asm volatile("s_waitcnt vmcnt(8)" ::: "memory"); // batch ks+1 landed
        } else if (ks == 14) {
            asm volatile("s_waitcnt vmcnt(0)" ::: "memory"); // final batch landed
        }
        if (ks < 15) __builtin_amdgcn_s_barrier();           // next buffer ready
        cur ^= 65536;
    }

#undef STAGE

    // ---- fused score epilogue (full head per block -> final logits) ----
    const int b = bi >> 2;
    const int sbase = (bi & 3) * 256;

    __syncthreads();                       // K-loop fully drained
    int* tl = (int*)(smem + 98304);
    int* lcnt = (int*)(smem + 98816);
    if (tid == 0) *lcnt = 0;
    __syncthreads();
    if (tid < 128) {
        if (best[tid * B_ + b] == bj) {
            int slot2 = atomicAdd(lcnt, 1);   // LDS atomic
            tl[slot2] = tid;
        }
    }
    __syncthreads();
    const int n = *lcnt;

    const int t_idx = tid >> 4, seg = tid & 15;
    const int sblk = wave & 3, thalf = wave >> 2;

    for (int slice = 0; slice < 4; ++slice) {
        // P-slice write: rows [slice*64, +64) come from waves wm == slice>>1,
        // acc i-blocks io..io+3.
        if (wm == (slice >> 1)) {
            const int io = (slice & 1) * 4;
#pragma unroll
            for (int i2 = 0; i2 < 4; ++i2) {
#pragma unroll
                for (int j = 0; j < 4; ++j) {
                    int col = wn * 64 + j * 16 + fr;
                    int g = col >> 3;
                    int cb = (col & 7) * 2;
#pragma unroll
                    for (int r = 0; r < 4; ++r) {
                        int rr = i2 * 16 + quad * 4 + r;
                        int gs = (g & 24) | ((g ^ rr) & 7);
                        float v = lrelu(acc[io + i2][j][r]);
                        uint32 u = __float_as_uint(v);
                        *(unsigned short*)(smem +         rr * 512 + gs * 16 + cb) = (unsigned short)(u >> 16);
                        float lo = v - __uint_as_float(u & 0xffff0000u);
                        *(unsigned short*)(smem + 32768 + rr * 512 + gs * 16 + cb) =
                            (unsigned short)(__float_as_uint(lo) >> 16);
                    }
                }
            }
        }
        __syncthreads();

        for (int tc = 0; tc < n; tc += 32) {
            int nn = min(32, n - tc);
            if (t_idx < nn) {
                int tt = tl[tc + t_idx];
                const float* qp = qv + ((size_t)tt * B_ + b) * Q_ + seg * 16;
                float4 f0 = *(const float4*)(qp);
                float4 f1 = *(const float4*)(qp + 4);
                float4 f2 = *(const float4*)(qp + 8);
                float4 f3 = *(const float4*)(qp + 12);
                uint4 h0 = make_uint4(pack_hi2(f0.x, f0.y), pack_hi2(f0.z, f0.w),
                                      pack_hi2(f1.x, f1.y), pack_hi2(f1.z, f1.w));
                uint4 h1 = make_uint4(pack_hi2(f2.x, f2.y), pack_hi2(f2.z, f2.w),
                                      pack_hi2(f3.x, f3.y), pack_hi2(f3.z, f3.w));
                uint4 l0 = make_uint4(pack_hi2(resid(f0.x), resid(f0.y)), pack_hi2(resid(f0.z), resid(f0.w)),
                                      pack_hi2(resid(f1.x), resid(f1.y)), pack_hi2(resid(f1.z), resid(f1.w)));
                uint4 l1 = make_uint4(pack_hi2(resid(f2.x), resid(f2.y)), pack_hi2(resid(f2.z), resid(f2.w)),
                                      pack_hi2(resid(f3.x), resid(f3.y)), pack_hi2(resid(f3.z), resid(f3.w)));
                int g0 = seg * 2, g1 = seg * 2 + 1;
                int gs0 = (g0 & 24) | ((g0 ^ t_idx) & 7);
                int gs1 = (g1 & 24) | ((g1 ^ t_idx) & 7);
                *(uint4*)(smem + 65536 + t_idx * 512 + gs0 * 16) = h0;
                *(uint4*)(smem + 65536 + t_idx * 512 + gs1 * 16) = h1;
                *(uint4*)(smem + 81920 + t_idx * 512 + gs0 * 16) = l0;
                *(uint4*)(smem + 81920 + t_idx * 512 + gs1 * 16) = l1;
            }
            __syncthreads();

            f32x4 sc = {0.f, 0.f, 0.f, 0.f};
            const bool act = (thalf == 0) || (nn > 16);
            if (act) {
                const int srow = sblk * 16 + fr;
                const int tloc = thalf * 16 + fr;
#pragma unroll
                for (int ks2 = 0; ks2 < 8; ++ks2) {
                    int kb = ks2 * 4 + quad;
                    int ko = ((kb & 24) | ((kb ^ xr) & 7)) * 16;
                    bf16x8 ph = *(const bf16x8*)(smem +         srow * 512 + ko);
                    bf16x8 pl = *(const bf16x8*)(smem + 32768 + srow * 512 + ko);
                    bf16x8 qh = *(const bf16x8*)(smem + 65536 + tloc * 512 + ko);
                    bf16x8 ql = *(const bf16x8*)(smem + 81920 + tloc * 512 + ko);
                    sc = __builtin_amdgcn_mfma_f32_16x16x32_bf16(qh, ph, sc, 0, 0, 0);
                    sc = __builtin_amdgcn_mfma_f32_16x16x32_bf16(qh, pl, sc, 0, 0, 0);
                    sc = __builtin_amdgcn_mfma_f32_16x16x32_bf16(ql, ph, sc, 0, 0, 0);
                }
            }
            int sg = sbase + slice * 64 + sblk * 16 + fr;
#pragma unroll
            for (int r = 0; r < 4; ++r) {
                int t0 = thalf * 16 + quad * 4 + r;
                if (t0 < nn) {
                    int tg = tl[tc + t0];
                    bufs[((size_t)tg * B_ + b) * S_ + sg] = sc[r];
                }
            }
            __syncthreads();
        }
        __syncthreads();
    }
}

// ---------------------------------------------------------------------------
// Masked softmax over complete logits (single buf).
// ---------------------------------------------------------------------------
__global__ __launch_bounds__(256) void softmax_kernel(
    const float* __restrict__ bufs, float* __restrict__ out,
    const int* __restrict__ mask) {
    const int row = blockIdx.x;
    const int b = row & (B_ - 1);
    const float* w0 = bufs + (size_t)row * S_;
    float* w = out + (size_t)row * S_;
    const int* mrow = mask + (size_t)b * S_;
    const int tid = threadIdx.x;

    float4 va = *(const float4*)(w0 + tid * 4);
    int4 mm = *(const int4*)(mrow + tid * 4);
    float x0 = mm.x ? -INFINITY : va.x;
    float x1 = mm.y ? -INFINITY : va.y;
    float x2 = mm.z ? -INFINITY : va.z;
    float x3 = mm.w ? -INFINITY : va.w;

    float lmax = fmaxf(fmaxf(x0, x1), fmaxf(x2, x3));
#pragma unroll
    for (int off = 32; off >= 1; off >>= 1)
        lmax = fmaxf(lmax, __shfl_down(lmax, off));

    __shared__ float redmax[4];
    __shared__ float redsum[4];
    const int wave = tid >> 6, lane = tid & 63;
    if (lane == 0) redmax[wave] = lmax;
    __syncthreads();
    float gmax = fmaxf(fmaxf(redmax[0], redmax[1]), fmaxf(redmax[2], redmax[3]));

    float e0 = mm.x ? 0.f : __expf(x0 - gmax);
    float e1 = mm.y ? 0.f : __expf(x1 - gmax);
    float e2 = mm.z ? 0.f : __expf(x2 - gmax);
    float e3 = mm.w ? 0.f : __expf(x3 - gmax);
    float lsum = e0 + e1 + e2 + e3;
#pragma unroll
    for (int off = 32; off >= 1; off >>= 1)
        lsum += __shfl_down(lsum, off);
    if (lane == 0) redsum[wave] = lsum;
    __syncthreads();
    float gsum = redsum[0] + redsum[1] + redsum[2] + redsum[3];
    float rinv = 1.0f / gsum;

    *(float4*)(w + tid * 4) = make_float4(e0 * rinv, e1 * rinv, e2 * rinv, e3 * rinv);
}

// ---------------------------------------------------------------------------
extern "C" void kernel_launch(void* const* d_in, const int* in_sizes, int n_in,
                              void* d_out, int out_size, void* d_ws, size_t ws_size,
                              hipStream_t stream) {
    float* src  = (float*)d_in[0];               // (B,S,E) fp32
    const int* mask = (const int*)d_in[1];       // (B,S)
    const float* qv = (const float*)d_in[2];     // (T,B,Q) fp32
    float* Wsrc = (float*)d_in[3];               // (H*Q,E) fp32
    const float* Wopt = (const float*)d_in[4];   // (H,Q)
    float* out = (float*)d_out;                  // (T,B,S)

    // ws layout: bufs (16 MiB) | best (64 KiB pad) | Apk (64 MiB) | Wpk (4 MiB)
    const size_t bufs_bytes = (size_t)T_ * B_ * S_ * sizeof(float);   // 16 MiB
    const size_t apk_off = bufs_bytes + 65536;
    const size_t wpk_off = apk_off + (size_t)B_ * S_ * E_ * sizeof(float);
    const size_t need    = wpk_off + (size_t)F_ * E_ * sizeof(float);

    float* bufs = (float*)d_ws;
    int* best = (int*)((char*)d_ws + bufs_bytes);

    // Out-of-place pack into ws if it fits; else verified in-place fallback.
    float* apk = (ws_size >= need) ? (float*)((char*)d_ws + apk_off) : src;
    float* wpk = (ws_size >= need) ? (float*)((char*)d_ws + wpk_off) : Wsrc;

    hipLaunchKernelGGL(prep_kernel, dim3(SRC_BLOCKS + W_BLOCKS + HS_BLOCKS), dim3(256),
                       0, stream, src, apk, Wsrc, wpk, qv, Wopt, best);
    hipLaunchKernelGGL(proj_score_kernel, dim3(512), dim3(512), 0, stream,
                       (const unsigned char*)apk, (const unsigned char*)wpk,
                       qv, best, bufs);
    hipLaunchKernelGGL(softmax_kernel, dim3(T_ * B_), dim3(256), 0, stream,
                       bufs, out, mask);
}

// Round 8
// 183.512 us; speedup vs baseline: 1.5261x; 1.5261x over previous
//
#include <hip/hip_runtime.h>
#include <hip/hip_bf16.h>
#include <math.h>

#define B_ 32
#define S_ 1024
#define E_ 512
#define T_ 128
#define Q_ 256
#define H_ 4
#define F_ (H_ * Q_)      // 1024
#define M_ (B_ * S_)      // 32768

typedef _Float16 f16x8 __attribute__((ext_vector_type(8)));
typedef float f32x4 __attribute__((ext_vector_type(4)));
typedef unsigned int uint32;

__device__ __forceinline__ float lrelu(float x) { return x > 0.0f ? x : 0.01f * x; }

// pack two floats -> two fp16 (RTN) in one u32
__device__ __forceinline__ uint32 packh2(float a, float b) {
    union { _Float16 h[2]; uint32 u; } v;
    v.h[0] = (_Float16)a; v.h[1] = (_Float16)b;
    return v.u;
}
__device__ __forceinline__ unsigned short packh1(float a) {
    union { _Float16 h; unsigned short u; } v;
    v.h = (_Float16)a;
    return v.u;
}

#define GLOAD_LDS16(g, l)                                                       \
    __builtin_amdgcn_global_load_lds(                                           \
        (const __attribute__((address_space(1))) void*)(g),                     \
        (__attribute__((address_space(3))) void*)(l), 16, 0, 0)

#define SRC_BLOCKS 16384      // src windows / 16
#define W_BLOCKS   512        // W_src windows / 16
#define HS_BLOCKS  1024       // head-select: wave per (t,b), 4 waves/block

// ---------------------------------------------------------------------------
// Prep: pack src/W_src IN PLACE to fp16 (RTN) per 64-float window: the 64
// fp16 occupy the window's first 128B (second half stale). Window handled by
// 16 lanes of ONE wave: all lanes' loads retire before the store instruction
// issues (SIMD order), so the shrink-in-place is race-free (r1-proven form).
// + per-(t,b) argmax head into best[].
// ---------------------------------------------------------------------------
__global__ __launch_bounds__(256) void prep_kernel(
    float* src, float* wsrc,
    const float* __restrict__ qv, const float* __restrict__ Wopt,
    int* __restrict__ best) {
    const int blk = blockIdx.x;
    if (blk < SRC_BLOCKS + W_BLOCKS) {
        float* base = (blk < SRC_BLOCKS) ? src : wsrc;
        const size_t woff = (size_t)((blk < SRC_BLOCKS) ? blk : (blk - SRC_BLOCKS)) * 16;
        const int tid = threadIdx.x;
        const size_t c = woff + (tid >> 4);
        const int j = tid & 15;
        float* wp = base + c * 64;
        float4 v = *(const float4*)(wp + j * 4);
        uint2 o = make_uint2(packh2(v.x, v.y), packh2(v.z, v.w));
        *(uint2*)((char*)wp + j * 8) = o;
    } else {
        const int wave = threadIdx.x >> 6, lane = threadIdx.x & 63;
        const int idx = (blk - SRC_BLOCKS - W_BLOCKS) * 4 + wave;   // t*B + b
        const float4 qq = *(const float4*)(qv + (size_t)idx * Q_ + lane * 4);
        float s[4];
#pragma unroll
        for (int h = 0; h < 4; ++h) {
            float4 w = *(const float4*)(Wopt + h * Q_ + lane * 4);
            s[h] = qq.x * w.x + qq.y * w.y + qq.z * w.z + qq.w * w.w;
        }
#pragma unroll
        for (int off = 32; off >= 1; off >>= 1) {
#pragma unroll
            for (int h = 0; h < 4; ++h) s[h] += __shfl_down(s[h], off);
        }
        if (lane == 0) {
            int bh = 0; float bs = s[0];
            if (s[1] > bs) { bs = s[1]; bh = 1; }
            if (s[2] > bs) { bs = s[2]; bh = 2; }
            if (s[3] > bs) { bs = s[3]; bh = 3; }
            best[idx] = bh;
        }
    }
}

// ---------------------------------------------------------------------------
// Fused proj+score, fp16-single (r6 skeleton verbatim, hi/lo sections and
// split-3-MFMA removed). Per step: stage A(8KB)+B(8KB) via 4 gload_lds/wave
// (vmcnt ledger rescaled: batch=4 -> vmcnt(4)); frag reads 8x16B/lane; 16
// MFMAs (f32_16x16x32_f16). Swizzle algebra identical to r6 (16B group = 8
// fp16; slot = g ^ ((row>>1)&3); pre-swizzled source = swizzled read).
// Window layout: row pitch 2048B, step ks at byte (ks>>1)*256 + (ks&1)*64
// (same hb formula as r6 — fp16 window packs 64 elems into first 128B).
// ---------------------------------------------------------------------------
__global__ __launch_bounds__(256, 2) void proj_score_kernel(
    const unsigned char* __restrict__ Apk,   // fp16-packed src (windowed)
    const unsigned char* __restrict__ Wpk,   // fp16-packed W_src (windowed)
    const float* __restrict__ qv,            // (T,B,Q) fp32
    const int* __restrict__ best,            // (T*B)
    float* __restrict__ bufs)                // 2 x (T,B,S) in ws
{
    __shared__ uint4 smem4[4096];            // 64 KB
    char* smem = (char*)smem4;
    // K-loop dbuf: buf@0, buf@16384; each 16KB: A[0,8K) B[8K,16K)
    // Epilogue: P [0,16K) (64 rows x 256B)  Q [32K,40K) (32 rows x 256B)
    //           tl [48K,+512) lcnt @48K+512

    const int bid = blockIdx.x;
    const int xcd = bid & 7;
    const int q_ = bid >> 3;                 // 0..255 within XCD
    const int bi = xcd * 32 + (q_ >> 3);     // 0..255 (M tile)
    const int bj = q_ & 7;                   // 0..7   (N tile)

    const int tid = threadIdx.x;
    const int wave = tid >> 6, lane = tid & 63;
    const int wm = wave >> 1, wn = wave & 1;
    const int quad = lane >> 4;
    const int fr = lane & 15;
    const int xr = fr & 7;

    const size_t Abase = (size_t)(bi * 128) * 2048;
    const size_t Wbase = (size_t)(bj * 128) * 2048;

    // --- staging lane mapping (16 rows x 4 slots per wave-instr) ---
    const int r16 = lane >> 2;                         // row within 16-row chunk
    const int slot = lane & 3;                         // 16B slot within 64B chunk
    const int sgb = ((slot ^ ((r16 >> 1) & 3)) & 3) * 16;  // pre-swizzled src group
    const unsigned char* gA = Apk + Abase + (size_t)(wave * 32 + r16) * 2048 + sgb;
    const unsigned char* gW = Wpk + Wbase + (size_t)(wave * 32 + r16) * 2048 + sgb;

    // --- compute lane mapping ---
    const int koB = ((quad ^ ((fr >> 1) & 3)) & 3) * 16;   // swizzled read slot
    const int aoff = (wm * 64 + fr) * 64 + koB;
    const int boff = (wn * 64 + fr) * 64 + koB;

    f32x4 acc[4][4] = {};

#define STAGE(bufb_, ks_) do {                                                 \
    const int hb_ = ((ks_) >> 1) * 256 + ((ks_) & 1) * 64;                     \
    _Pragma("unroll")                                                          \
    for (int c_ = 0; c_ < 2; ++c_) {                                           \
        const unsigned char* a_ = gA + (size_t)c_ * 16 * 2048 + hb_;           \
        const unsigned char* w_ = gW + (size_t)c_ * 16 * 2048 + hb_;           \
        char* l_ = smem + (bufb_) + wave * 2048 + c_ * 1024;                   \
        GLOAD_LDS16(a_, l_);                                                   \
        GLOAD_LDS16(w_, l_ + 8192);                                            \
    }                                                                          \
} while (0)

    STAGE(0, 0);
    STAGE(16384, 1);
    asm volatile("s_waitcnt vmcnt(4)" ::: "memory");   // batch 0 landed (b1 in flight)
    __builtin_amdgcn_s_barrier();

    int cur = 0;
#pragma unroll 1
    for (int ks = 0; ks < 16; ++ks) {
        f16x8 ah[4], bh4[4];
#pragma unroll
        for (int i_ = 0; i_ < 4; ++i_) {
            ah[i_]  = *(const f16x8*)(smem + cur +        aoff + i_ * 1024);
            bh4[i_] = *(const f16x8*)(smem + cur + 8192 + boff + i_ * 1024);
        }
        asm volatile("s_waitcnt lgkmcnt(0)" ::: "memory");  // my reads of cur done
        __builtin_amdgcn_s_barrier();                       // everyone's reads done
        if (ks < 14) STAGE(cur, ks + 2);                    // overwrite cur (prefetch)
        __builtin_amdgcn_s_setprio(1);
#pragma unroll
        for (int i_ = 0; i_ < 4; ++i_)
#pragma unroll
            for (int j_ = 0; j_ < 4; ++j_) {
                acc[i_][j_] = __builtin_amdgcn_mfma_f32_16x16x32_f16(ah[i_], bh4[j_], acc[i_][j_], 0, 0, 0);
            }
        __builtin_amdgcn_s_setprio(0);
        if (ks < 14) {
            asm volatile("s_waitcnt vmcnt(4)" ::: "memory"); // batch ks+1 landed
        } else if (ks == 14) {
            asm volatile("s_waitcnt vmcnt(0)" ::: "memory"); // final batch landed
        }
        if (ks < 15) __builtin_amdgcn_s_barrier();           // next buffer ready
        cur ^= 16384;
    }

#undef STAGE

    // ---- fused score epilogue ----
    const int b = bi >> 3;
    const int sbase = (bi & 7) * 128;
    const int h = bj >> 1;
    const int qoff = (bj & 1) * 128;
    float* buf = bufs + (size_t)(bj & 1) * ((size_t)T_ * B_ * S_);

    __syncthreads();                       // K-loop LDS reads done (full drain)
    int* tl = (int*)(smem + 49152);
    int* lcnt = (int*)(smem + 49152 + 512);
    if (tid == 0) *lcnt = 0;
    __syncthreads();
    if (tid < 128) {
        if (best[tid * B_ + b] == h) {
            int slot2 = atomicAdd(lcnt, 1);   // LDS atomic
            tl[slot2] = tid;
        }
    }
    __syncthreads();
    const int n = *lcnt;

    const int t_idx = tid >> 3, seg = tid & 7;

    for (int half = 0; half < 2; ++half) {
        if (wm == half) {
#pragma unroll
            for (int i = 0; i < 4; ++i) {
#pragma unroll
                for (int j = 0; j < 4; ++j) {
                    int col = wn * 64 + j * 16 + fr;
                    int g = col >> 3;
                    int cb = (col & 7) * 2;
#pragma unroll
                    for (int r = 0; r < 4; ++r) {
                        int rr = i * 16 + quad * 4 + r;
                        int gs = (g & 8) | ((g ^ rr) & 7);
                        *(unsigned short*)(smem + rr * 256 + gs * 16 + cb) =
                            packh1(lrelu(acc[i][j][r]));
                    }
                }
            }
        }
        __syncthreads();

        for (int tc = 0; tc < n; tc += 32) {
            int nn = min(32, n - tc);
            if (t_idx < nn) {
                int tt = tl[tc + t_idx];
                const float* qp = qv + ((size_t)tt * B_ + b) * Q_ + qoff + seg * 16;
                float4 f0 = *(const float4*)(qp);
                float4 f1 = *(const float4*)(qp + 4);
                float4 f2 = *(const float4*)(qp + 8);
                float4 f3 = *(const float4*)(qp + 12);
                uint4 h0 = make_uint4(packh2(f0.x, f0.y), packh2(f0.z, f0.w),
                                      packh2(f1.x, f1.y), packh2(f1.z, f1.w));
                uint4 h1 = make_uint4(packh2(f2.x, f2.y), packh2(f2.z, f2.w),
                                      packh2(f3.x, f3.y), packh2(f3.z, f3.w));
                int g0 = seg * 2, g1 = seg * 2 + 1;
                int gs0 = (g0 & 8) | ((g0 ^ t_idx) & 7);
                int gs1 = (g1 & 8) | ((g1 ^ t_idx) & 7);
                *(uint4*)(smem + 32768 + t_idx * 256 + gs0 * 16) = h0;
                *(uint4*)(smem + 32768 + t_idx * 256 + gs1 * 16) = h1;
            }
            __syncthreads();

            f32x4 sc0 = {0.f, 0.f, 0.f, 0.f}, sc1 = {0.f, 0.f, 0.f, 0.f};
#pragma unroll
            for (int ks = 0; ks < 4; ++ks) {
                int kb = ks * 4 + quad;
                int ko = ((kb & 8) | ((kb ^ xr) & 7)) * 16;
                int prow = wave * 16 + fr;
                f16x8 ph = *(const f16x8*)(smem + prow * 256 + ko);
                f16x8 qh0 = *(const f16x8*)(smem + 32768 + fr * 256 + ko);
                sc0 = __builtin_amdgcn_mfma_f32_16x16x32_f16(qh0, ph, sc0, 0, 0, 0);
                if (nn > 16) {
                    f16x8 qh1 = *(const f16x8*)(smem + 32768 + (16 + fr) * 256 + ko);
                    sc1 = __builtin_amdgcn_mfma_f32_16x16x32_f16(qh1, ph, sc1, 0, 0, 0);
                }
            }
            int sg = sbase + half * 64 + wave * 16 + fr;
#pragma unroll
            for (int r = 0; r < 4; ++r) {
                int t0 = quad * 4 + r;
                if (t0 < nn) {
                    int tg = tl[tc + t0];
                    buf[((size_t)tg * B_ + b) * S_ + sg] = sc0[r];
                }
                int t1 = 16 + quad * 4 + r;
                if (t1 < nn) {
                    int tg = tl[tc + t1];
                    buf[((size_t)tg * B_ + b) * S_ + sg] = sc1[r];
                }
            }
            __syncthreads();
        }
        __syncthreads();
    }
}

// ---------------------------------------------------------------------------
// Masked softmax: logits = buf0 + buf1 (q-half partials), masked, softmax.
// ---------------------------------------------------------------------------
__global__ __launch_bounds__(256) void softmax_kernel(
    const float* __restrict__ bufs, float* __restrict__ out,
    const int* __restrict__ mask) {
    const int row = blockIdx.x;
    const int b = row & (B_ - 1);
    const float* w0 = bufs + (size_t)row * S_;
    const float* w1 = w0 + (size_t)T_ * B_ * S_;
    float* w = out + (size_t)row * S_;
    const int* mrow = mask + (size_t)b * S_;
    const int tid = threadIdx.x;

    float4 va = *(const float4*)(w0 + tid * 4);
    float4 vb = *(const float4*)(w1 + tid * 4);
    int4 mm = *(const int4*)(mrow + tid * 4);
    float x0 = mm.x ? -INFINITY : (va.x + vb.x);
    float x1 = mm.y ? -INFINITY : (va.y + vb.y);
    float x2 = mm.z ? -INFINITY : (va.z + vb.z);
    float x3 = mm.w ? -INFINITY : (va.w + vb.w);

    float lmax = fmaxf(fmaxf(x0, x1), fmaxf(x2, x3));
#pragma unroll
    for (int off = 32; off >= 1; off >>= 1)
        lmax = fmaxf(lmax, __shfl_down(lmax, off));

    __shared__ float redmax[4];
    __shared__ float redsum[4];
    const int wave = tid >> 6, lane = tid & 63;
    if (lane == 0) redmax[wave] = lmax;
    __syncthreads();
    float gmax = fmaxf(fmaxf(redmax[0], redmax[1]), fmaxf(redmax[2], redmax[3]));

    float e0 = mm.x ? 0.f : __expf(x0 - gmax);
    float e1 = mm.y ? 0.f : __expf(x1 - gmax);
    float e2 = mm.z ? 0.f : __expf(x2 - gmax);
    float e3 = mm.w ? 0.f : __expf(x3 - gmax);
    float lsum = e0 + e1 + e2 + e3;
#pragma unroll
    for (int off = 32; off >= 1; off >>= 1)
        lsum += __shfl_down(lsum, off);
    if (lane == 0) redsum[wave] = lsum;
    __syncthreads();
    float gsum = redsum[0] + redsum[1] + redsum[2] + redsum[3];
    float rinv = 1.0f / gsum;

    *(float4*)(w + tid * 4) = make_float4(e0 * rinv, e1 * rinv, e2 * rinv, e3 * rinv);
}

// ---------------------------------------------------------------------------
extern "C" void kernel_launch(void* const* d_in, const int* in_sizes, int n_in,
                              void* d_out, int out_size, void* d_ws, size_t ws_size,
                              hipStream_t stream) {
    float* src  = (float*)d_in[0];               // (B,S,E) — fp16-packed in place
    const int* mask = (const int*)d_in[1];       // (B,S)
    const float* qv = (const float*)d_in[2];     // (T,B,Q) fp32
    float* Wsrc = (float*)d_in[3];               // (H*Q,E) — fp16-packed in place
    const float* Wopt = (const float*)d_in[4];   // (H,Q)
    float* out = (float*)d_out;                  // (T,B,S)

    // ws: bufs = 2 x 16 MiB score partials, then best[] (T*B ints)
    float* bufs = (float*)d_ws;
    int* best = (int*)((char*)d_ws + 2 * (size_t)T_ * B_ * S_ * sizeof(float));

    hipLaunchKernelGGL(prep_kernel, dim3(SRC_BLOCKS + W_BLOCKS + HS_BLOCKS), dim3(256),
                       0, stream, src, Wsrc, qv, Wopt, best);
    hipLaunchKernelGGL(proj_score_kernel, dim3(2048), dim3(256), 0, stream,
                       (const unsigned char*)src, (const unsigned char*)Wsrc,
                       qv, best, bufs);
    hipLaunchKernelGGL(softmax_kernel, dim3(T_ * B_), dim3(256), 0, stream,
                       bufs, out, mask);
}

// Round 9
// 165.811 us; speedup vs baseline: 1.6890x; 1.1068x over previous
//
#include <hip/hip_runtime.h>
#include <hip/hip_bf16.h>
#include <math.h>

#define B_ 32
#define S_ 1024
#define E_ 512
#define T_ 128
#define Q_ 256
#define H_ 4
#define F_ (H_ * Q_)      // 1024
#define M_ (B_ * S_)      // 32768

typedef _Float16 f16x8 __attribute__((ext_vector_type(8)));
typedef float f32x4 __attribute__((ext_vector_type(4)));
typedef unsigned int uint32;

__device__ __forceinline__ float lrelu(float x) { return x > 0.0f ? x : 0.01f * x; }

__device__ __forceinline__ uint32 packh2(float a, float b) {
    union { _Float16 h[2]; uint32 u; } v;
    v.h[0] = (_Float16)a; v.h[1] = (_Float16)b;
    return v.u;
}
__device__ __forceinline__ unsigned short packh1(float a) {
    union { _Float16 h; unsigned short u; } v;
    v.h = (_Float16)a;
    return v.u;
}

#define GLOAD_LDS16(g, l)                                                       \
    __builtin_amdgcn_global_load_lds(                                           \
        (const __attribute__((address_space(1))) void*)(g),                     \
        (__attribute__((address_space(3))) void*)(l), 16, 0, 0)

#define SRCW_BLOCKS 4096      // src windows / 64
#define WW_BLOCKS   128       // W_src windows / 64
#define HS_BLOCKS   1024      // head-select: wave per (t,b), 4 waves/block

// ---------------------------------------------------------------------------
// Prep: pack src/W_src IN PLACE to fp16 (RTN) per 64-float window (64 fp16 in
// the window's first 128B). Window handled by 4 lanes of ONE wave (64B read,
// 32B write per lane): wave-lockstep loads retire before the store instr
// issues -> in-place-safe (r1/r8-proven pattern). + per-(t,b) argmax head.
// Deeper per-thread work than r8 (4x fewer blocks) to fix prep's ~2.6 TB/s.
// ---------------------------------------------------------------------------
__global__ __launch_bounds__(256) void prep_kernel(
    float* src, float* wsrc,
    const float* __restrict__ qv, const float* __restrict__ Wopt,
    int* __restrict__ best) {
    const int blk = blockIdx.x;
    if (blk < SRCW_BLOCKS + WW_BLOCKS) {
        float* base = (blk < SRCW_BLOCKS) ? src : wsrc;
        const size_t w0 = (size_t)((blk < SRCW_BLOCKS) ? blk : (blk - SRCW_BLOCKS)) * 64;
        const int tid = threadIdx.x;
        const size_t c = w0 + (tid >> 2);
        const int j = tid & 3;
        const float* rp = base + c * 64 + j * 16;
        float4 v0 = ((const float4*)rp)[0];
        float4 v1 = ((const float4*)rp)[1];
        float4 v2 = ((const float4*)rp)[2];
        float4 v3 = ((const float4*)rp)[3];
        uint4 o0 = make_uint4(packh2(v0.x, v0.y), packh2(v0.z, v0.w),
                              packh2(v1.x, v1.y), packh2(v1.z, v1.w));
        uint4 o1 = make_uint4(packh2(v2.x, v2.y), packh2(v2.z, v2.w),
                              packh2(v3.x, v3.y), packh2(v3.z, v3.w));
        char* op = (char*)(base + c * 64) + j * 32;
        ((uint4*)op)[0] = o0;
        ((uint4*)op)[1] = o1;
    } else {
        const int wave = threadIdx.x >> 6, lane = threadIdx.x & 63;
        const int idx = (blk - SRCW_BLOCKS - WW_BLOCKS) * 4 + wave;   // t*B + b
        const float4 qq = *(const float4*)(qv + (size_t)idx * Q_ + lane * 4);
        float s[4];
#pragma unroll
        for (int h = 0; h < 4; ++h) {
            float4 w = *(const float4*)(Wopt + h * Q_ + lane * 4);
            s[h] = qq.x * w.x + qq.y * w.y + qq.z * w.z + qq.w * w.w;
        }
#pragma unroll
        for (int off = 32; off >= 1; off >>= 1) {
#pragma unroll
            for (int h = 0; h < 4; ++h) s[h] += __shfl_down(s[h], off);
        }
        if (lane == 0) {
            int bh = 0; float bs = s[0];
            if (s[1] > bs) { bs = s[1]; bh = 1; }
            if (s[2] > bs) { bs = s[2]; bh = 2; }
            if (s[3] > bs) { bs = s[3]; bh = 3; }
            best[idx] = bh;
        }
    }
}

// ---------------------------------------------------------------------------
// Fused proj+score, fp16, 128x256 tile = FULL HEAD per block (bj = head).
// 4 waves, wave-tile 64x128 (acc[4][8] = 128 VGPR; fits the 256-VGPR cap of
// __launch_bounds__(256,2) -- 2nd arg is CUDA-style min-BLOCKS (r7 evidence:
// (512,2) capped at 124 and spilled)). K-loop = r8's verified counted-vmcnt
// skeleton; 6 gload_lds/wave/step (A 2 + B 4) -> vmcnt(6). Same r8 window
// format + 2-bit XOR swizzle. Epilogue: single P (128 rows x 512B, r7's
// verified 5-bit-granule swizzle gs=(g&24)|((g^row)&7)), full-Q score (8 ks,
// 1 MFMA each), SINGLE output buf (no q-half partials).
// LDS 76800B x 2 blocks = 150KB/CU.
// ---------------------------------------------------------------------------
__global__ __launch_bounds__(256, 2) void proj_score_kernel(
    const unsigned char* __restrict__ Apk,   // fp16-packed src (windowed)
    const unsigned char* __restrict__ Wpk,   // fp16-packed W_src (windowed)
    const float* __restrict__ qv,            // (T,B,Q) fp32
    const int* __restrict__ best,            // (T*B)
    float* __restrict__ bufs)                // (T,B,S) logits in ws
{
    __shared__ uint4 smem4[4800];            // 76800 B
    char* smem = (char*)smem4;
    // K-loop dbuf: buf@0, buf@24576; each 24KB: A[0,8K) B[8K,24K)
    // Epilogue: P @0 (128 rows x 512B = 64KB)  Q @65536 (16 rows x 512B = 8KB)
    //           tl @73728 (+512)  lcnt @74240

    const int bid = blockIdx.x;
    const int xcd = bid & 7;
    const int q_ = bid >> 3;                 // 0..127 within XCD
    const int bi = xcd * 32 + (q_ >> 2);     // 0..255 (M tile, 128 rows)
    const int bj = q_ & 3;                   // head 0..3 (N tile, 256 cols)

    const int tid = threadIdx.x;
    const int wave = tid >> 6, lane = tid & 63;
    const int wm = wave >> 1, wn = wave & 1;
    const int quad = lane >> 4;
    const int fr = lane & 15;
    const int xr = fr & 7;

    const size_t Abase = (size_t)(bi * 128) * 2048;
    const size_t Wbase = (size_t)(bj * 256) * 2048;

    // --- staging lane mapping (16 rows x 4 slots per wave-instr) ---
    const int r16 = lane >> 2;
    const int slot = lane & 3;
    const int sgb = ((slot ^ ((r16 >> 1) & 3)) & 3) * 16;  // pre-swizzled src group
    const unsigned char* gA = Apk + Abase + (size_t)(wave * 32 + r16) * 2048 + sgb;
    const unsigned char* gW = Wpk + Wbase + (size_t)(wave * 64 + r16) * 2048 + sgb;

    // --- compute lane mapping ---
    const int koB = ((quad ^ ((fr >> 1) & 3)) & 3) * 16;   // swizzled read slot
    const int aoff = (wm * 64 + fr) * 64 + koB;
    const int boff = (wn * 128 + fr) * 64 + koB;

    f32x4 acc[4][8] = {};

#define STAGE(bufb_, ks_) do {                                                 \
    const int hb_ = ((ks_) >> 1) * 256 + ((ks_) & 1) * 64;                     \
    _Pragma("unroll")                                                          \
    for (int c_ = 0; c_ < 2; ++c_) {                                           \
        GLOAD_LDS16(gA + (size_t)c_ * 16 * 2048 + hb_,                         \
                    smem + (bufb_) + (wave * 2 + c_) * 1024);                  \
    }                                                                          \
    _Pragma("unroll")                                                          \
    for (int c_ = 0; c_ < 4; ++c_) {                                           \
        GLOAD_LDS16(gW + (size_t)c_ * 16 * 2048 + hb_,                         \
                    smem + (bufb_) + 8192 + (wave * 4 + c_) * 1024);           \
    }                                                                          \
} while (0)

    STAGE(0, 0);
    STAGE(24576, 1);
    asm volatile("s_waitcnt vmcnt(6)" ::: "memory");   // batch 0 landed (b1 in flight)
    __builtin_amdgcn_s_barrier();

    int cur = 0;
#pragma unroll 1
    for (int ks = 0; ks < 16; ++ks) {
        f16x8 ah[4], bh8[8];
#pragma unroll
        for (int i_ = 0; i_ < 4; ++i_)
            ah[i_] = *(const f16x8*)(smem + cur + aoff + i_ * 1024);
#pragma unroll
        for (int j_ = 0; j_ < 8; ++j_)
            bh8[j_] = *(const f16x8*)(smem + cur + 8192 + boff + j_ * 1024);
        asm volatile("s_waitcnt lgkmcnt(0)" ::: "memory");  // my reads of cur done
        __builtin_amdgcn_s_barrier();                       // everyone's reads done
        if (ks < 14) STAGE(cur, ks + 2);                    // overwrite cur (prefetch)
        __builtin_amdgcn_s_setprio(1);
#pragma unroll
        for (int i_ = 0; i_ < 4; ++i_)
#pragma unroll
            for (int j_ = 0; j_ < 8; ++j_) {
                acc[i_][j_] = __builtin_amdgcn_mfma_f32_16x16x32_f16(ah[i_], bh8[j_], acc[i_][j_], 0, 0, 0);
            }
        __builtin_amdgcn_s_setprio(0);
        if (ks < 14) {
            asm volatile("s_waitcnt vmcnt(6)" ::: "memory"); // batch ks+1 landed
        } else if (ks == 14) {
            asm volatile("s_waitcnt vmcnt(0)" ::: "memory"); // final batch landed
        }
        if (ks < 15) __builtin_amdgcn_s_barrier();           // next buffer ready
        cur ^= 24576;
    }

#undef STAGE

    // ---- fused score epilogue (full head -> final logits, single buf) ----
    const int b = bi >> 3;
    const int sbase = (bi & 7) * 128;

    __syncthreads();                       // K-loop LDS reads done
    int* tl = (int*)(smem + 73728);
    int* lcnt = (int*)(smem + 74240);
    if (tid == 0) *lcnt = 0;
    __syncthreads();
    if (tid < 128) {
        if (best[tid * B_ + b] == bj) {
            int slot2 = atomicAdd(lcnt, 1);   // LDS atomic
            tl[slot2] = tid;
        }
    }
    __syncthreads();
    const int n = *lcnt;

    // P write: every wave writes its own acc (P covers all 128 rows at once)
#pragma unroll
    for (int i = 0; i < 4; ++i) {
#pragma unroll
        for (int j = 0; j < 8; ++j) {
            int col = wn * 128 + j * 16 + fr;
            int g = col >> 3;
            int cb = (col & 7) * 2;
#pragma unroll
            for (int r = 0; r < 4; ++r) {
                int rr = wm * 64 + i * 16 + quad * 4 + r;
                int gs = (g & 24) | ((g ^ rr) & 7);
                *(unsigned short*)(smem + rr * 512 + gs * 16 + cb) =
                    packh1(lrelu(acc[i][j][r]));
            }
        }
    }
    __syncthreads();

    const int t_idx = tid >> 4, seg = tid & 15;

    for (int tc = 0; tc < n; tc += 16) {
        int nn = min(16, n - tc);
        if (t_idx < nn) {
            int tt = tl[tc + t_idx];
            const float* qp = qv + ((size_t)tt * B_ + b) * Q_ + seg * 16;
            float4 f0 = *(const float4*)(qp);
            float4 f1 = *(const float4*)(qp + 4);
            float4 f2 = *(const float4*)(qp + 8);
            float4 f3 = *(const float4*)(qp + 12);
            uint4 h0 = make_uint4(packh2(f0.x, f0.y), packh2(f0.z, f0.w),
                                  packh2(f1.x, f1.y), packh2(f1.z, f1.w));
            uint4 h1 = make_uint4(packh2(f2.x, f2.y), packh2(f2.z, f2.w),
                                  packh2(f3.x, f3.y), packh2(f3.z, f3.w));
            int g0 = seg * 2, g1 = seg * 2 + 1;
            int gs0 = (g0 & 24) | ((g0 ^ t_idx) & 7);
            int gs1 = (g1 & 24) | ((g1 ^ t_idx) & 7);
            *(uint4*)(smem + 65536 + t_idx * 512 + gs0 * 16) = h0;
            *(uint4*)(smem + 65536 + t_idx * 512 + gs1 * 16) = h1;
        }
        __syncthreads();

#pragma unroll
        for (int sub = 0; sub < 2; ++sub) {
            const int sblk = wave * 2 + sub;
            const int srow = sblk * 16 + fr;
            f32x4 sc = {0.f, 0.f, 0.f, 0.f};
#pragma unroll
            for (int ks2 = 0; ks2 < 8; ++ks2) {
                int kb = ks2 * 4 + quad;
                int ko = ((kb & 24) | ((kb ^ xr) & 7)) * 16;
                f16x8 ph = *(const f16x8*)(smem + srow * 512 + ko);
                f16x8 qh = *(const f16x8*)(smem + 65536 + fr * 512 + ko);
                sc = __builtin_amdgcn_mfma_f32_16x16x32_f16(qh, ph, sc, 0, 0, 0);
            }
            int sg = sbase + sblk * 16 + fr;
#pragma unroll
            for (int r = 0; r < 4; ++r) {
                int tloc = quad * 4 + r;
                if (tloc < nn) {
                    int tg = tl[tc + tloc];
                    bufs[((size_t)tg * B_ + b) * S_ + sg] = sc[r];
                }
            }
        }
        __syncthreads();
    }
}

// ---------------------------------------------------------------------------
// Masked softmax over complete logits (single buf).
// ---------------------------------------------------------------------------
__global__ __launch_bounds__(256) void softmax_kernel(
    const float* __restrict__ bufs, float* __restrict__ out,
    const int* __restrict__ mask) {
    const int row = blockIdx.x;
    const int b = row & (B_ - 1);
    const float* w0 = bufs + (size_t)row * S_;
    float* w = out + (size_t)row * S_;
    const int* mrow = mask + (size_t)b * S_;
    const int tid = threadIdx.x;

    float4 va = *(const float4*)(w0 + tid * 4);
    int4 mm = *(const int4*)(mrow + tid * 4);
    float x0 = mm.x ? -INFINITY : va.x;
    float x1 = mm.y ? -INFINITY : va.y;
    float x2 = mm.z ? -INFINITY : va.z;
    float x3 = mm.w ? -INFINITY : va.w;

    float lmax = fmaxf(fmaxf(x0, x1), fmaxf(x2, x3));
#pragma unroll
    for (int off = 32; off >= 1; off >>= 1)
        lmax = fmaxf(lmax, __shfl_down(lmax, off));

    __shared__ float redmax[4];
    __shared__ float redsum[4];
    const int wave = tid >> 6, lane = tid & 63;
    if (lane == 0) redmax[wave] = lmax;
    __syncthreads();
    float gmax = fmaxf(fmaxf(redmax[0], redmax[1]), fmaxf(redmax[2], redmax[3]));

    float e0 = mm.x ? 0.f : __expf(x0 - gmax);
    float e1 = mm.y ? 0.f : __expf(x1 - gmax);
    float e2 = mm.z ? 0.f : __expf(x2 - gmax);
    float e3 = mm.w ? 0.f : __expf(x3 - gmax);
    float lsum = e0 + e1 + e2 + e3;
#pragma unroll
    for (int off = 32; off >= 1; off >>= 1)
        lsum += __shfl_down(lsum, off);
    if (lane == 0) redsum[wave] = lsum;
    __syncthreads();
    float gsum = redsum[0] + redsum[1] + redsum[2] + redsum[3];
    float rinv = 1.0f / gsum;

    *(float4*)(w + tid * 4) = make_float4(e0 * rinv, e1 * rinv, e2 * rinv, e3 * rinv);
}

// ---------------------------------------------------------------------------
extern "C" void kernel_launch(void* const* d_in, const int* in_sizes, int n_in,
                              void* d_out, int out_size, void* d_ws, size_t ws_size,
                              hipStream_t stream) {
    float* src  = (float*)d_in[0];               // (B,S,E) — fp16-packed in place
    const int* mask = (const int*)d_in[1];       // (B,S)
    const float* qv = (const float*)d_in[2];     // (T,B,Q) fp32
    float* Wsrc = (float*)d_in[3];               // (H*Q,E) — fp16-packed in place
    const float* Wopt = (const float*)d_in[4];   // (H,Q)
    float* out = (float*)d_out;                  // (T,B,S)

    // ws: bufs = (T,B,S) logits (16 MiB), then best[] (T*B ints)
    float* bufs = (float*)d_ws;
    int* best = (int*)((char*)d_ws + (size_t)T_ * B_ * S_ * sizeof(float));

    hipLaunchKernelGGL(prep_kernel, dim3(SRCW_BLOCKS + WW_BLOCKS + HS_BLOCKS), dim3(256),
                       0, stream, src, Wsrc, qv, Wopt, best);
    hipLaunchKernelGGL(proj_score_kernel, dim3(1024), dim3(256), 0, stream,
                       (const unsigned char*)src, (const unsigned char*)Wsrc,
                       qv, best, bufs);
    hipLaunchKernelGGL(softmax_kernel, dim3(T_ * B_), dim3(256), 0, stream,
                       bufs, out, mask);
}